// Round 1
// baseline (1236.886 us; speedup 1.0000x reference)
//
#include <hip/hip_runtime.h>

// HubertWithKmeans: argmin_c ||x - c|| over C=2048 centers for M=32768 tokens, D=768.
// argmin_c dist == argmin_c (||c||^2 - 2 x.c)  (||x||^2 per-token constant, sqrt monotone)
constexpr int MM = 32768;   // B*T tokens
constexpr int NN = 2048;    // clusters
constexpr int KK = 768;     // dim

constexpr int TM = 128;     // tokens per block
constexpr int TN = 256;     // clusters per block
constexpr int TK = 32;      // k-tile
constexpr int THREADS = 256;

__global__ __launch_bounds__(256)
void init_ws_kernel(unsigned long long* __restrict__ w) {
    w[blockIdx.x * 256 + threadIdx.x] = 0xFFFFFFFFFFFFFFFFull;
}

__global__ __launch_bounds__(64)
void csq_kernel(const float* __restrict__ cc, float* __restrict__ csq) {
    const int cl = blockIdx.x;
    const int lane = threadIdx.x;
    const float4* row = reinterpret_cast<const float4*>(cc + (size_t)cl * KK);
    float s = 0.f;
#pragma unroll
    for (int w = 0; w < KK / (4 * 64); ++w) {   // 3 float4 per lane
        float4 v = row[w * 64 + lane];
        s = fmaf(v.x, v.x, s); s = fmaf(v.y, v.y, s);
        s = fmaf(v.z, v.z, s); s = fmaf(v.w, v.w, s);
    }
#pragma unroll
    for (int off = 32; off > 0; off >>= 1) s += __shfl_xor(s, off, 64);
    if (lane == 0) csq[cl] = s;
}

__global__ __launch_bounds__(THREADS, 2)
void argmin_kernel(const float* __restrict__ A, const float* __restrict__ Bc,
                   const float* __restrict__ csq,
                   unsigned long long* __restrict__ ws64) {
    // Transposed LDS tiles; +4 pad keeps b128 reads 16B-aligned and
    // staging-write conflicts at ~4-way (only on the small staging fraction).
    __shared__ float As[TK][TM + 4];  // [k][token],  row stride 132 floats
    __shared__ float Bs[TK][TN + 4];  // [k][cluster], row stride 260 floats

    const int tid = threadIdx.x;
    const int tx = tid & 15;        // cluster group: clusters q*64 + tx*4 + jj
    const int ty = tid >> 4;        // token group (0..15): tokens ty*8 .. +7
    const int kq = tid & 7;         // staging k-quad
    const int row0 = tid >> 3;      // staging row 0..31
    const int tbase = blockIdx.x * TM;
    const int cb = blockIdx.y * TN;

    float acc[8][16];
#pragma unroll
    for (int i = 0; i < 8; ++i)
#pragma unroll
        for (int j = 0; j < 16; ++j) acc[i][j] = 0.f;

    // Prologue: prefetch k-tile 0 into registers.
    float4 av[4], bv[8];
#pragma unroll
    for (int p = 0; p < 4; ++p)
        av[p] = *reinterpret_cast<const float4*>(&A[(size_t)(tbase + row0 + p*32)*KK + kq*4]);
#pragma unroll
    for (int p = 0; p < 8; ++p)
        bv[p] = *reinterpret_cast<const float4*>(&Bc[(size_t)(cb + row0 + p*32)*KK + kq*4]);

    for (int k0 = 0; k0 < KK; k0 += TK) {
        __syncthreads();                     // prev compute done reading LDS
#pragma unroll
        for (int p = 0; p < 4; ++p) {        // transposed scatter: As[k][token]
            const int t = row0 + p*32;
            As[kq*4+0][t] = av[p].x; As[kq*4+1][t] = av[p].y;
            As[kq*4+2][t] = av[p].z; As[kq*4+3][t] = av[p].w;
        }
#pragma unroll
        for (int p = 0; p < 8; ++p) {        // Bs[k][cluster]
            const int c = row0 + p*32;
            Bs[kq*4+0][c] = bv[p].x; Bs[kq*4+1][c] = bv[p].y;
            Bs[kq*4+2][c] = bv[p].z; Bs[kq*4+3][c] = bv[p].w;
        }
        __syncthreads();

        // Prefetch next k-tile while computing this one (hides L2/HBM latency).
        const int kn = k0 + TK;
        if (kn < KK) {
#pragma unroll
            for (int p = 0; p < 4; ++p)
                av[p] = *reinterpret_cast<const float4*>(&A[(size_t)(tbase + row0 + p*32)*KK + kn + kq*4]);
#pragma unroll
            for (int p = 0; p < 8; ++p)
                bv[p] = *reinterpret_cast<const float4*>(&Bc[(size_t)(cb + row0 + p*32)*KK + kn + kq*4]);
        }

#pragma unroll 4
        for (int k = 0; k < TK; ++k) {
            float4 a0 = *reinterpret_cast<const float4*>(&As[k][ty*8]);
            float4 a1 = *reinterpret_cast<const float4*>(&As[k][ty*8 + 4]);
            float4 b0 = *reinterpret_cast<const float4*>(&Bs[k][tx*4]);
            float4 b1 = *reinterpret_cast<const float4*>(&Bs[k][64 + tx*4]);
            float4 b2 = *reinterpret_cast<const float4*>(&Bs[k][128 + tx*4]);
            float4 b3 = *reinterpret_cast<const float4*>(&Bs[k][192 + tx*4]);
            const float aa[8]  = {a0.x,a0.y,a0.z,a0.w, a1.x,a1.y,a1.z,a1.w};
            const float bb[16] = {b0.x,b0.y,b0.z,b0.w, b1.x,b1.y,b1.z,b1.w,
                                  b2.x,b2.y,b2.z,b2.w, b3.x,b3.y,b3.z,b3.w};
#pragma unroll
            for (int i = 0; i < 8; ++i)
#pragma unroll
                for (int j = 0; j < 16; ++j)
                    acc[i][j] = fmaf(aa[i], bb[j], acc[i][j]);
        }
    }

    // Epilogue: score = ||c||^2 - 2*x.c ; per-thread argmin in ascending
    // cluster order with strict < (matches jnp.argmin first-min semantics).
    float best[8];
    int bidx[8];
#pragma unroll
    for (int i = 0; i < 8; ++i) { best[i] = 3.4e38f; bidx[i] = 0; }
#pragma unroll
    for (int q = 0; q < 4; ++q) {
        float4 cs = *reinterpret_cast<const float4*>(&csq[cb + q*64 + tx*4]);
        const float cq[4] = {cs.x, cs.y, cs.z, cs.w};
#pragma unroll
        for (int jj = 0; jj < 4; ++jj) {
            const int c = cb + q*64 + tx*4 + jj;
#pragma unroll
            for (int i = 0; i < 8; ++i) {
                const float sc = cq[jj] - 2.0f * acc[i][q*4 + jj];
                if (sc < best[i]) { best[i] = sc; bidx[i] = c; }
            }
        }
    }

    __syncthreads();   // everyone done reading As before aliasing it
    float (*rv)[16] = reinterpret_cast<float(*)[16]>(&As[0][0]);
    int   (*ri)[16] = reinterpret_cast<int(*)[16]>(
                          reinterpret_cast<char*>(&As[0][0]) + TM * 16 * 4);
#pragma unroll
    for (int i = 0; i < 8; ++i) {
        rv[ty*8 + i][tx] = best[i];
        ri[ty*8 + i][tx] = bidx[i];
    }
    __syncthreads();
    if (tid < TM) {
        float bv2 = rv[tid][0];
        int bi2 = ri[tid][0];
#pragma unroll
        for (int t = 1; t < 16; ++t) {
            const float v = rv[tid][t];
            const int ix = ri[tid][t];
            if (v < bv2 || (v == bv2 && ix < bi2)) { bv2 = v; bi2 = ix; }
        }
        // Monotone key for non-total-ordered fp32 bits; ties -> smaller index.
        const unsigned int b = __float_as_uint(bv2);
        const unsigned int key = (b & 0x80000000u) ? ~b : (b | 0x80000000u);
        const unsigned long long pk =
            ((unsigned long long)key << 32) | (unsigned long long)(unsigned int)bi2;
        atomicMin(&ws64[tbase + tid], pk);
    }
}

__global__ __launch_bounds__(256)
void unpack_kernel(const unsigned long long* __restrict__ w, int* __restrict__ out) {
    const int i = blockIdx.x * 256 + threadIdx.x;
    out[i] = (int)(unsigned int)(w[i] & 0xFFFFFFFFull);
}

extern "C" void kernel_launch(void* const* d_in, const int* in_sizes, int n_in,
                              void* d_out, int out_size, void* d_ws, size_t ws_size,
                              hipStream_t stream) {
    const float* embed   = (const float*)d_in[0];   // [32768][768] fp32
    const float* centers = (const float*)d_in[1];   // [2048][768] fp32
    int* out = (int*)d_out;                         // [32768] int32
    unsigned long long* ws64 = (unsigned long long*)d_ws;          // 256 KB
    float* csq = (float*)((char*)d_ws + (size_t)MM * 8);           // + 8 KB

    init_ws_kernel<<<MM / 256, 256, 0, stream>>>(ws64);
    csq_kernel<<<NN, 64, 0, stream>>>(centers, csq);
    argmin_kernel<<<dim3(MM / TM, NN / TN), THREADS, 0, stream>>>(embed, centers, csq, ws64);
    unpack_kernel<<<MM / 256, 256, 0, stream>>>(ws64, out);
}

// Round 3
// 447.645 us; speedup vs baseline: 2.7631x; 2.7631x over previous
//
#include <hip/hip_runtime.h>

// argmin_c ||x-c|| == argmin_c (||c||^2 - 2 x.c). Cross-term via 3 f16 MFMA
// GEMMs (exact hi/lo split of fp32, lo*lo dropped ~2^-20 rel) at bf16 rate.
typedef __fp16 f16x2 __attribute__((ext_vector_type(2)));
typedef __fp16 f16x8 __attribute__((ext_vector_type(8)));
typedef float f32x4 __attribute__((ext_vector_type(4)));

constexpr int MM = 32768;   // B*T tokens
constexpr int NN = 2048;    // clusters
constexpr int KK = 768;     // dim
constexpr int BM = 128;     // tokens per block
constexpr int BN = 128;     // clusters per block
constexpr int BK = 32;      // k-tile

__global__ __launch_bounds__(256)
void init_ws_kernel(unsigned long long* __restrict__ w) {
    w[blockIdx.x * 256 + threadIdx.x] = 0xFFFFFFFFFFFFFFFFull;
}

__global__ __launch_bounds__(64)
void csq_kernel(const float* __restrict__ cc, float* __restrict__ csq) {
    const int cl = blockIdx.x;
    const int lane = threadIdx.x;
    const float4* row = reinterpret_cast<const float4*>(cc + (size_t)cl * KK);
    float s = 0.f;
#pragma unroll
    for (int w = 0; w < KK / (4 * 64); ++w) {
        float4 v = row[w * 64 + lane];
        s = fmaf(v.x, v.x, s); s = fmaf(v.y, v.y, s);
        s = fmaf(v.z, v.z, s); s = fmaf(v.w, v.w, s);
    }
#pragma unroll
    for (int off = 32; off > 0; off >>= 1) s += __shfl_xor(s, off, 64);
    if (lane == 0) csq[cl] = s;
}

__device__ __forceinline__ unsigned bc(f16x2 h) {
    return __builtin_bit_cast(unsigned, h);
}

__global__ __launch_bounds__(256, 2)
void argmin_mfma_kernel(const float* __restrict__ A, const float* __restrict__ Bc,
                        const float* __restrict__ csq,
                        unsigned long long* __restrict__ ws64) {
    // Four f16 tiles [128 rows][32 k] packed as u32[128][16], row stride 20 u32
    // (stride 20: staging-store and frag-read bank patterns both uniform 8/bank).
    __shared__ unsigned lds[4 * 128 * 20];   // 40960 B: AH | AL | BH | BL
    constexpr int AH = 0, AL = 2560, BH = 5120;

    const int tid  = threadIdx.x;
    const int lane = tid & 63;
    const int ln15 = lane & 15;
    const int quad = lane >> 4;
    const int wave = tid >> 6;
    const int wm = wave >> 1, wn = wave & 1;   // wave tile: rows wm*64+, cols wn*64+
    const int tbase = blockIdx.x * BM;
    const int cb    = blockIdx.y * BN;

    // Staging: thread -> (row = tid>>1, k-half = tid&1), 16 consecutive floats.
    const int sr  = tid >> 1;
    const int skh = tid & 1;
    const float* gA = A  + (size_t)(tbase + sr) * KK + skh * 16;
    const float* gB = Bc + (size_t)(cb   + sr) * KK + skh * 16;
    const int wword = sr * 20 + skh * 8;

    f32x4 acc[4][4];
#pragma unroll
    for (int i = 0; i < 4; ++i)
#pragma unroll
        for (int j = 0; j < 4; ++j) { f32x4 z = {0.f,0.f,0.f,0.f}; acc[i][j] = z; }

    // Prologue prefetch of k-tile 0.
    float4 av[4], bv[4];
#pragma unroll
    for (int p = 0; p < 4; ++p) {
        av[p] = *(const float4*)(gA + p * 4);
        bv[p] = *(const float4*)(gB + p * 4);
    }

    // Fragment LDS word addresses (constant across k-tiles).
    int aw[4], bw[4];
#pragma unroll
    for (int i = 0; i < 4; ++i) {
        aw[i] = AH + (wm * 64 + i * 16 + ln15) * 20 + quad * 4;
        bw[i] = BH + (wn * 64 + i * 16 + ln15) * 20 + quad * 4;
    }

    for (int k0 = 0; k0 < KK; k0 += BK) {
        __syncthreads();                      // previous compute done with LDS
        // Convert fp32 -> f16 hi/lo (RTZ pack) and store tiles.
#pragma unroll
        for (int h = 0; h < 2; ++h) {
            float4 v0 = av[2*h], v1 = av[2*h+1];
            f16x2 h00 = __builtin_amdgcn_cvt_pkrtz(v0.x, v0.y);
            f16x2 h01 = __builtin_amdgcn_cvt_pkrtz(v0.z, v0.w);
            f16x2 h10 = __builtin_amdgcn_cvt_pkrtz(v1.x, v1.y);
            f16x2 h11 = __builtin_amdgcn_cvt_pkrtz(v1.z, v1.w);
            f16x2 l00 = __builtin_amdgcn_cvt_pkrtz(v0.x-(float)h00[0], v0.y-(float)h00[1]);
            f16x2 l01 = __builtin_amdgcn_cvt_pkrtz(v0.z-(float)h01[0], v0.w-(float)h01[1]);
            f16x2 l10 = __builtin_amdgcn_cvt_pkrtz(v1.x-(float)h10[0], v1.y-(float)h10[1]);
            f16x2 l11 = __builtin_amdgcn_cvt_pkrtz(v1.z-(float)h11[0], v1.w-(float)h11[1]);
            uint4 hv = {bc(h00), bc(h01), bc(h10), bc(h11)};
            uint4 lv = {bc(l00), bc(l01), bc(l10), bc(l11)};
            *(uint4*)&lds[AH + wword + 4*h] = hv;
            *(uint4*)&lds[AL + wword + 4*h] = lv;

            float4 w0 = bv[2*h], w1 = bv[2*h+1];
            f16x2 g00 = __builtin_amdgcn_cvt_pkrtz(w0.x, w0.y);
            f16x2 g01 = __builtin_amdgcn_cvt_pkrtz(w0.z, w0.w);
            f16x2 g10 = __builtin_amdgcn_cvt_pkrtz(w1.x, w1.y);
            f16x2 g11 = __builtin_amdgcn_cvt_pkrtz(w1.z, w1.w);
            f16x2 m00 = __builtin_amdgcn_cvt_pkrtz(w0.x-(float)g00[0], w0.y-(float)g00[1]);
            f16x2 m01 = __builtin_amdgcn_cvt_pkrtz(w0.z-(float)g01[0], w0.w-(float)g01[1]);
            f16x2 m10 = __builtin_amdgcn_cvt_pkrtz(w1.x-(float)g10[0], w1.y-(float)g10[1]);
            f16x2 m11 = __builtin_amdgcn_cvt_pkrtz(w1.z-(float)g11[0], w1.w-(float)g11[1]);
            uint4 gv = {bc(g00), bc(g01), bc(g10), bc(g11)};
            uint4 mv = {bc(m00), bc(m01), bc(m10), bc(m11)};
            *(uint4*)&lds[BH + wword + 4*h]        = gv;
            *(uint4*)&lds[BH + 2560 + wword + 4*h] = mv;
        }
        __syncthreads();

        // Prefetch next k-tile during compute.
        const int kn = k0 + BK;
        if (kn < KK) {
#pragma unroll
            for (int p = 0; p < 4; ++p) {
                av[p] = *(const float4*)(gA + kn + p * 4);
                bv[p] = *(const float4*)(gB + kn + p * 4);
            }
        }

        // Fragments: A[m=lane&15][k=quad*8+j] -> contiguous 16B per lane.
        f16x8 a_h[4], a_l[4], b_h[4], b_l[4];
#pragma unroll
        for (int i = 0; i < 4; ++i) {
            a_h[i] = *(const f16x8*)&lds[aw[i]];
            a_l[i] = *(const f16x8*)&lds[aw[i] + 2560];
            b_h[i] = *(const f16x8*)&lds[bw[i]];
            b_l[i] = *(const f16x8*)&lds[bw[i] + 2560];
        }
#pragma unroll
        for (int i = 0; i < 4; ++i)
#pragma unroll
            for (int j = 0; j < 4; ++j) {
                acc[i][j] = __builtin_amdgcn_mfma_f32_16x16x32_f16(a_h[i], b_h[j], acc[i][j], 0, 0, 0);
                acc[i][j] = __builtin_amdgcn_mfma_f32_16x16x32_f16(a_h[i], b_l[j], acc[i][j], 0, 0, 0);
                acc[i][j] = __builtin_amdgcn_mfma_f32_16x16x32_f16(a_l[i], b_h[j], acc[i][j], 0, 0, 0);
            }
    }

    // Epilogue: score = csq - 2*dot; C/D layout col=lane&15, row=quad*4+reg.
    float csq4[4];
#pragma unroll
    for (int j = 0; j < 4; ++j) csq4[j] = csq[cb + wn * 64 + j * 16 + ln15];

    float bval[16]; int bidx[16];
#pragma unroll
    for (int i = 0; i < 4; ++i)
#pragma unroll
        for (int r = 0; r < 4; ++r) {
            const int rid = i * 4 + r;
            float bv_ = csq4[0] - 2.0f * acc[i][0][r];
            int   bi_ = cb + wn * 64 + ln15;
#pragma unroll
            for (int j = 1; j < 4; ++j) {
                const float s = csq4[j] - 2.0f * acc[i][j][r];
                const int   c = cb + wn * 64 + j * 16 + ln15;
                if (s < bv_) { bv_ = s; bi_ = c; }   // ascending c, strict <
            }
            bval[rid] = bv_; bidx[rid] = bi_;
        }

    // Reduce across the 16 col-lanes of each quad (same rows per quad).
#pragma unroll
    for (int off = 1; off < 16; off <<= 1) {
#pragma unroll
        for (int rid = 0; rid < 16; ++rid) {
            const float ov = __shfl_xor(bval[rid], off, 64);
            const int   oi = __shfl_xor(bidx[rid], off, 64);
            if (ov < bval[rid] || (ov == bval[rid] && oi < bidx[rid])) {
                bval[rid] = ov; bidx[rid] = oi;
            }
        }
    }

    __syncthreads();                 // tiles dead; reuse LDS for row table
    float* vtab = (float*)&lds[0];   // [128][2]
    int*   itab = (int*)&lds[256];   // [128][2]
    if (ln15 == 0) {
#pragma unroll
        for (int i = 0; i < 4; ++i)
#pragma unroll
            for (int r = 0; r < 4; ++r) {
                const int row = wm * 64 + i * 16 + quad * 4 + r;
                vtab[row * 2 + wn] = bval[i * 4 + r];
                itab[row * 2 + wn] = bidx[i * 4 + r];
            }
    }
    __syncthreads();
    if (tid < 128) {
        float v0 = vtab[tid * 2]; int i0 = itab[tid * 2];
        const float v1 = vtab[tid * 2 + 1]; const int i1 = itab[tid * 2 + 1];
        if (v1 < v0 || (v1 == v0 && i1 < i0)) { v0 = v1; i0 = i1; }
        const unsigned b   = __float_as_uint(v0);
        const unsigned key = (b & 0x80000000u) ? ~b : (b | 0x80000000u);
        const unsigned long long pk =
            ((unsigned long long)key << 32) | (unsigned long long)(unsigned)i0;
        atomicMin(&ws64[tbase + tid], pk);
    }
}

__global__ __launch_bounds__(256)
void unpack_kernel(const unsigned long long* __restrict__ w, int* __restrict__ out) {
    const int i = blockIdx.x * 256 + threadIdx.x;
    out[i] = (int)(unsigned)(w[i] & 0xFFFFFFFFull);
}

extern "C" void kernel_launch(void* const* d_in, const int* in_sizes, int n_in,
                              void* d_out, int out_size, void* d_ws, size_t ws_size,
                              hipStream_t stream) {
    const float* embed   = (const float*)d_in[0];   // [32768][768] fp32
    const float* centers = (const float*)d_in[1];   // [2048][768] fp32
    int* out = (int*)d_out;                         // [32768] int32
    unsigned long long* ws64 = (unsigned long long*)d_ws;   // 256 KB
    float* csq = (float*)((char*)d_ws + (size_t)MM * 8);    // + 8 KB

    init_ws_kernel<<<MM / 256, 256, 0, stream>>>(ws64);
    csq_kernel<<<NN, 64, 0, stream>>>(centers, csq);
    argmin_mfma_kernel<<<dim3(MM / BM, NN / BN), 256, 0, stream>>>(embed, centers, csq, ws64);
    unpack_kernel<<<MM / 256, 256, 0, stream>>>(ws64, out);
}